// Round 12
// baseline (92.826 us; speedup 1.0000x reference)
//
#include <hip/hip_runtime.h>

#define DIM 8192
#define NLAYERS 8
#define SIMT 1024       // sim threads: 16 waves (4/SIMD), 8 amps/thread
#define QFB 2048
#define QFT 256
#define ROWS_PER_BLOCK 4

typedef float floatx4 __attribute__((ext_vector_type(4)));
typedef float f2 __attribute__((ext_vector_type(2)));

// swizzle: even 4-way for all round patterns below [GF(2)-verified, run in R11]
__device__ __forceinline__ int swz(int i) { return i ^ ((i >> 4) & 15); }

// ---------------------------------------------------------------------------
// Kernel 1: statevector sim, 1 block, 1024 threads. qubit q <-> bit p = 12-q.
// Thread t holds 8 amps. Layout cycle, 3 LDS rounds/layer (24 barriers total):
//   C: i = (t<<3)|l                         l = bits 0-2; lane bits = i 3-8
//   A: i = (t&7)|(l<<3)|((t>>3)<<6)         l = bits 3-5; i bits 6-8 = lane 3-5
//   D: i = ((t>>1)&511)|(l<<9)|((t&1)<<12)  l = bits 9-11; bit 12 = lane bit 0
// Per layer: RX(0-2) local -> T1(C->A) -> RX(3-5) local
//          -> RX(6-8) via shfl_xor(8/16/32)        [barrier-free, new]
//          -> T2(A->D) -> RX(9-11) local -> RX(12) shfl_xor(1) -> RZ diag
//          -> T3(D->C) = CNOT fused (suffix-parity inverse gather).
// All LDS patterns (Wc,Ra,Wa,Rd,Wd,Rc) identical to R11's verified set.
// RX in packed-f2 form (v_pk_mul/v_pk_fma), proven bit-exact since R10.
// ---------------------------------------------------------------------------
__global__ __launch_bounds__(SIMT) void sim_kernel(const float* __restrict__ params,
                                                   float* __restrict__ outR,
                                                   float* __restrict__ outM) {
    __shared__ f2 buf[2][DIM];   // 128 KiB ping-pong
    const int t = threadIdx.x;

    f2 a[8];
#pragma unroll
    for (int l = 0; l < 8; ++l) a[l] = (f2){0.f, 0.f};
    if (t == 0) a[0] = (f2){1.f, 0.f};

    int pp = 0;  // ping-pong parity

    for (int layer = 0; layer < NLAYERS; ++layer) {
        const float* __restrict__ prx = params + layer * 26;
        const float* __restrict__ prz = prx + 13;

        float cb[13], sb[13];
#pragma unroll
        for (int p = 0; p < 13; ++p) __sincosf(0.5f * prx[12 - p], &sb[p], &cb[p]);

        // ---- RX bits 0..2 (register-local, layout C) ----
#pragma unroll
        for (int k = 0; k < 3; ++k) {
            const f2 c2 = {cb[k], cb[k]};
            const f2 sg = {sb[k], -sb[k]};
#pragma unroll
            for (int l0 = 0; l0 < 8; ++l0) {
                if (!(l0 & (1 << k))) {
                    const int l1 = l0 | (1 << k);
                    const f2 a0 = a[l0], a1 = a[l1];
                    a[l0] = c2 * a0 + __builtin_shufflevector(a1, a1, 1, 0) * sg;
                    a[l1] = c2 * a1 + __builtin_shufflevector(a0, a0, 1, 0) * sg;
                }
            }
        }

        // ---- T1: C -> A ----
        {
            f2* __restrict__ B = buf[pp]; pp ^= 1;
#pragma unroll
            for (int l = 0; l < 8; ++l) B[swz((t << 3) | l)] = a[l];
            __syncthreads();
#pragma unroll
            for (int l = 0; l < 8; ++l)
                a[l] = B[swz((t & 7) | (l << 3) | ((t >> 3) << 6))];
        }

        // ---- RX bits 3..5 (register-local, layout A) ----
#pragma unroll
        for (int k = 0; k < 3; ++k) {
            const f2 c2 = {cb[3 + k], cb[3 + k]};
            const f2 sg = {sb[3 + k], -sb[3 + k]};
#pragma unroll
            for (int l0 = 0; l0 < 8; ++l0) {
                if (!(l0 & (1 << k))) {
                    const int l1 = l0 | (1 << k);
                    const f2 a0 = a[l0], a1 = a[l1];
                    a[l0] = c2 * a0 + __builtin_shufflevector(a1, a1, 1, 0) * sg;
                    a[l1] = c2 * a1 + __builtin_shufflevector(a0, a0, 1, 0) * sg;
                }
            }
        }

        // ---- RX bits 6..8 (layout A, lane bits 3..5): shfl_xor, no barrier ----
#pragma unroll
        for (int k = 0; k < 3; ++k) {
            const f2 c2 = {cb[6 + k], cb[6 + k]};
            const f2 sg = {sb[6 + k], -sb[6 + k]};
            const int mask = 8 << k;   // 8, 16, 32
#pragma unroll
            for (int l = 0; l < 8; ++l) {
                f2 o;
                o.x = __shfl_xor(a[l].x, mask);
                o.y = __shfl_xor(a[l].y, mask);
                a[l] = c2 * a[l] + __builtin_shufflevector(o, o, 1, 0) * sg;
            }
        }

        // ---- T2: A -> D ----
        {
            f2* __restrict__ B = buf[pp]; pp ^= 1;
#pragma unroll
            for (int l = 0; l < 8; ++l)
                B[swz((t & 7) | (l << 3) | ((t >> 3) << 6))] = a[l];
            __syncthreads();
#pragma unroll
            for (int l = 0; l < 8; ++l)
                a[l] = B[swz(((t >> 1) & 511) | (l << 9) | ((t & 1) << 12))];
        }

        // ---- RX bits 9..11 (register-local, layout D) ----
#pragma unroll
        for (int k = 0; k < 3; ++k) {
            const f2 c2 = {cb[9 + k], cb[9 + k]};
            const f2 sg = {sb[9 + k], -sb[9 + k]};
#pragma unroll
            for (int l0 = 0; l0 < 8; ++l0) {
                if (!(l0 & (1 << k))) {
                    const int l1 = l0 | (1 << k);
                    const f2 a0 = a[l0], a1 = a[l1];
                    a[l0] = c2 * a0 + __builtin_shufflevector(a1, a1, 1, 0) * sg;
                    a[l1] = c2 * a1 + __builtin_shufflevector(a0, a0, 1, 0) * sg;
                }
            }
        }

        // ---- RX bit 12 (lane bit 0 in layout D): shfl_xor 1 ----
        {
            const f2 c2 = {cb[12], cb[12]};
            const f2 sg = {sb[12], -sb[12]};
#pragma unroll
            for (int l = 0; l < 8; ++l) {
                f2 o;
                o.x = __shfl_xor(a[l].x, 1);
                o.y = __shfl_xor(a[l].y, 1);
                a[l] = c2 * a[l] + __builtin_shufflevector(o, o, 1, 0) * sg;
            }
        }

        // ---- RZ diagonal (layout D): bits 0-8 = t>>1, 9-11 = l, 12 = t&1 ----
        float hz[13];
#pragma unroll
        for (int p = 0; p < 13; ++p) hz[p] = 0.5f * prz[12 - p];
        float phiT = 0.f;
#pragma unroll
        for (int p = 0; p < 9; ++p) phiT += (((t >> 1) >> p) & 1) ? hz[p] : -hz[p];
        phiT += (t & 1) ? hz[12] : -hz[12];
#pragma unroll
        for (int l = 0; l < 8; ++l) {
            float phi = phiT;
            phi += (l & 1) ? hz[9]  : -hz[9];
            phi += (l & 2) ? hz[10] : -hz[10];
            phi += (l & 4) ? hz[11] : -hz[11];
            float sp, cp;
            __sincosf(phi, &sp, &cp);
            a[l] = (f2){a[l].x * cp - a[l].y * sp, a[l].x * sp + a[l].y * cp};
        }

        // ---- T3: CNOT round, D -> canonical (inverse suffix-parity gather) ----
        {
            f2* __restrict__ B = buf[pp]; pp ^= 1;
#pragma unroll
            for (int l = 0; l < 8; ++l)
                B[swz(((t >> 1) & 511) | (l << 9) | ((t & 1) << 12))] = a[l];
            __syncthreads();
#pragma unroll
            for (int l = 0; l < 8; ++l) {
                const int c0 = (t << 3) | l;
                a[l] = B[swz(c0 ^ (c0 >> 1))];
            }
        }
    }

    // ---- write r, m (canonical: thread t owns amps [8t, 8t+8) ) ----
    {
        const float4 rv0 = make_float4(a[0].x, a[1].x, a[2].x, a[3].x);
        const float4 rv1 = make_float4(a[4].x, a[5].x, a[6].x, a[7].x);
        const float4 mv0 = make_float4(a[0].y, a[1].y, a[2].y, a[3].y);
        const float4 mv1 = make_float4(a[4].y, a[5].y, a[6].y, a[7].y);
        ((float4*)outR)[2 * t]     = rv0;
        ((float4*)outR)[2 * t + 1] = rv1;
        ((float4*)outM)[2 * t]     = mv0;
        ((float4*)outM)[2 * t + 1] = mv1;
    }
}

// ---------------------------------------------------------------------------
// Kernel 2: partials = r^T O r + m^T O m — byte-identical to the proven
// quad (one NT streaming pass, at the HBM/L3 read-BW floor).
// ---------------------------------------------------------------------------
__global__ __launch_bounds__(QFT) void quad_kernel(const float* __restrict__ O,
                                                   const float* __restrict__ R,
                                                   const float* __restrict__ M,
                                                   float* __restrict__ partials) {
    const int bi = blockIdx.x;
    const int t  = threadIdx.x;
    const float4* __restrict__ R4 = (const float4*)R;
    const float4* __restrict__ M4 = (const float4*)M;

    float acc = 0.f;
#pragma unroll
    for (int rr = 0; rr < ROWS_PER_BLOCK; ++rr) {
        const int i = bi * ROWS_PER_BLOCK + rr;
        const float ri = R[i];
        const float mi = M[i];
        const floatx4* __restrict__ Or = (const floatx4*)(O + (size_t)i * DIM);
#pragma unroll
        for (int it = 0; it < DIM / 4 / QFT; ++it) {   // 8 iterations
            const int j4 = t + it * QFT;
            const floatx4 o = __builtin_nontemporal_load(&Or[j4]);
            const float4 rj = R4[j4];
            const float4 mj = M4[j4];
            acc = fmaf(o.x, fmaf(ri, rj.x, mi * mj.x), acc);
            acc = fmaf(o.y, fmaf(ri, rj.y, mi * mj.y), acc);
            acc = fmaf(o.z, fmaf(ri, rj.z, mi * mj.z), acc);
            acc = fmaf(o.w, fmaf(ri, rj.w, mi * mj.w), acc);
        }
    }

#pragma unroll
    for (int off = 32; off > 0; off >>= 1) acc += __shfl_down(acc, off);
    __shared__ float wsum[QFT / 64];
    const int lane = t & 63, w = t >> 6;
    if (lane == 0) wsum[w] = acc;
    __syncthreads();
    if (t == 0) {
        float s = 0.f;
#pragma unroll
        for (int k = 0; k < QFT / 64; ++k) s += wsum[k];
        partials[bi] = s;
    }
}

__global__ __launch_bounds__(256) void reduce_kernel(const float* __restrict__ partials,
                                                     float* __restrict__ out) {
    const int t = threadIdx.x;
    float acc = 0.f;
#pragma unroll
    for (int k = 0; k < QFB / 256; ++k) acc += partials[t + k * 256];
#pragma unroll
    for (int off = 32; off > 0; off >>= 1) acc += __shfl_down(acc, off);
    __shared__ float wsum[4];
    const int lane = t & 63, w = t >> 6;
    if (lane == 0) wsum[w] = acc;
    __syncthreads();
    if (t == 0) out[0] = wsum[0] + wsum[1] + wsum[2] + wsum[3];
}

extern "C" void kernel_launch(void* const* d_in, const int* in_sizes, int n_in,
                              void* d_out, int out_size, void* d_ws, size_t ws_size,
                              hipStream_t stream) {
    const float* params = (const float*)d_in[0];   // 208 fp32
    const float* O      = (const float*)d_in[1];   // 8192*8192 fp32
    float* out = (float*)d_out;

    float* R        = (float*)d_ws;
    float* M        = R + DIM;
    float* partials = M + DIM;

    sim_kernel<<<1, SIMT, 0, stream>>>(params, R, M);
    quad_kernel<<<QFB, QFT, 0, stream>>>(O, R, M, partials);
    reduce_kernel<<<1, 256, 0, stream>>>(partials, out);
}

// Round 13
// 80.497 us; speedup vs baseline: 1.1532x; 1.1532x over previous
//
#include <hip/hip_runtime.h>

#define DIM 8192
#define NLAYERS 8
#define SIMT 1024       // 16 waves (4/SIMD), 8 amps/thread
#define NB 256          // 1 block per CU (128 KB LDS forces it)
#define QROWS (DIM / NB) // 32 rows of O per block

typedef float floatx4 __attribute__((ext_vector_type(4)));
typedef float f2 __attribute__((ext_vector_type(2)));

// swizzle: even 4-way for all round patterns below [GF(2)-verified, run in R11]
__device__ __forceinline__ int swz(int i) { return i ^ ((i >> 4) & 15); }

// ---------------------------------------------------------------------------
// Fused kernel: every block runs the FULL R11-verified sim redundantly
// (1 block/CU -> same wall time as one block; no inter-block communication,
// no fences), stores psi in its own LDS, then streams its 32 rows of O.
//   sim: layouts C->A->B->D->C, 4 ping-pong LDS rounds/layer, bit12 shfl,
//        packed-f2 RX (bit-exact since R10), scalar RZ (R3-verified).
//   quad: acc += O_ij*(r_i r_j + m_i m_j); rj/mj (8 cols) register-cached,
//         r_i/m_i LDS broadcast; NT loads on O (proven config).
// ---------------------------------------------------------------------------
__global__ __launch_bounds__(SIMT) void fused_kernel(const float* __restrict__ params,
                                                     const float* __restrict__ O,
                                                     float* __restrict__ partials) {
    __shared__ f2 buf[2][DIM];   // 128 KiB ping-pong; buf[0] holds psi afterwards
    const int t = threadIdx.x;

    f2 a[8];
#pragma unroll
    for (int l = 0; l < 8; ++l) a[l] = (f2){0.f, 0.f};
    if (t == 0) a[0] = (f2){1.f, 0.f};

    int pp = 0;  // ping-pong parity

    for (int layer = 0; layer < NLAYERS; ++layer) {
        const float* __restrict__ prx = params + layer * 26;
        const float* __restrict__ prz = prx + 13;

        float cb[13], sb[13];
#pragma unroll
        for (int p = 0; p < 13; ++p) __sincosf(0.5f * prx[12 - p], &sb[p], &cb[p]);

        // ---- RX bits 0..2 (register-local, layout C) ----
#pragma unroll
        for (int k = 0; k < 3; ++k) {
            const f2 c2 = {cb[k], cb[k]};
            const f2 sg = {sb[k], -sb[k]};
#pragma unroll
            for (int l0 = 0; l0 < 8; ++l0) {
                if (!(l0 & (1 << k))) {
                    const int l1 = l0 | (1 << k);
                    const f2 a0 = a[l0], a1 = a[l1];
                    a[l0] = c2 * a0 + __builtin_shufflevector(a1, a1, 1, 0) * sg;
                    a[l1] = c2 * a1 + __builtin_shufflevector(a0, a0, 1, 0) * sg;
                }
            }
        }

        // ---- T1: C -> A ----
        {
            f2* __restrict__ B = buf[pp]; pp ^= 1;
#pragma unroll
            for (int l = 0; l < 8; ++l) B[swz((t << 3) | l)] = a[l];
            __syncthreads();
#pragma unroll
            for (int l = 0; l < 8; ++l)
                a[l] = B[swz((t & 7) | (l << 3) | ((t >> 3) << 6))];
        }

        // ---- RX bits 3..5 (layout A) ----
#pragma unroll
        for (int k = 0; k < 3; ++k) {
            const f2 c2 = {cb[3 + k], cb[3 + k]};
            const f2 sg = {sb[3 + k], -sb[3 + k]};
#pragma unroll
            for (int l0 = 0; l0 < 8; ++l0) {
                if (!(l0 & (1 << k))) {
                    const int l1 = l0 | (1 << k);
                    const f2 a0 = a[l0], a1 = a[l1];
                    a[l0] = c2 * a0 + __builtin_shufflevector(a1, a1, 1, 0) * sg;
                    a[l1] = c2 * a1 + __builtin_shufflevector(a0, a0, 1, 0) * sg;
                }
            }
        }

        // ---- T2: A -> B ----
        {
            f2* __restrict__ B = buf[pp]; pp ^= 1;
#pragma unroll
            for (int l = 0; l < 8; ++l)
                B[swz((t & 7) | (l << 3) | ((t >> 3) << 6))] = a[l];
            __syncthreads();
#pragma unroll
            for (int l = 0; l < 8; ++l)
                a[l] = B[swz((t & 63) | (l << 6) | ((t >> 6) << 9))];
        }

        // ---- RX bits 6..8 (layout B) ----
#pragma unroll
        for (int k = 0; k < 3; ++k) {
            const f2 c2 = {cb[6 + k], cb[6 + k]};
            const f2 sg = {sb[6 + k], -sb[6 + k]};
#pragma unroll
            for (int l0 = 0; l0 < 8; ++l0) {
                if (!(l0 & (1 << k))) {
                    const int l1 = l0 | (1 << k);
                    const f2 a0 = a[l0], a1 = a[l1];
                    a[l0] = c2 * a0 + __builtin_shufflevector(a1, a1, 1, 0) * sg;
                    a[l1] = c2 * a1 + __builtin_shufflevector(a0, a0, 1, 0) * sg;
                }
            }
        }

        // ---- T3: B -> D ----
        {
            f2* __restrict__ B = buf[pp]; pp ^= 1;
#pragma unroll
            for (int l = 0; l < 8; ++l)
                B[swz((t & 63) | (l << 6) | ((t >> 6) << 9))] = a[l];
            __syncthreads();
#pragma unroll
            for (int l = 0; l < 8; ++l)
                a[l] = B[swz(((t >> 1) & 511) | (l << 9) | ((t & 1) << 12))];
        }

        // ---- RX bits 9..11 (layout D) ----
#pragma unroll
        for (int k = 0; k < 3; ++k) {
            const f2 c2 = {cb[9 + k], cb[9 + k]};
            const f2 sg = {sb[9 + k], -sb[9 + k]};
#pragma unroll
            for (int l0 = 0; l0 < 8; ++l0) {
                if (!(l0 & (1 << k))) {
                    const int l1 = l0 | (1 << k);
                    const f2 a0 = a[l0], a1 = a[l1];
                    a[l0] = c2 * a0 + __builtin_shufflevector(a1, a1, 1, 0) * sg;
                    a[l1] = c2 * a1 + __builtin_shufflevector(a0, a0, 1, 0) * sg;
                }
            }
        }

        // ---- RX bit 12 (lane bit 0 in layout D): shfl_xor 1 ----
        {
            const f2 c2 = {cb[12], cb[12]};
            const f2 sg = {sb[12], -sb[12]};
#pragma unroll
            for (int l = 0; l < 8; ++l) {
                f2 o;
                o.x = __shfl_xor(a[l].x, 1);
                o.y = __shfl_xor(a[l].y, 1);
                a[l] = c2 * a[l] + __builtin_shufflevector(o, o, 1, 0) * sg;
            }
        }

        // ---- RZ diagonal (layout D): bits 0-8 = t>>1, 9-11 = l, 12 = t&1 ----
        float hz[13];
#pragma unroll
        for (int p = 0; p < 13; ++p) hz[p] = 0.5f * prz[12 - p];
        float phiT = 0.f;
#pragma unroll
        for (int p = 0; p < 9; ++p) phiT += (((t >> 1) >> p) & 1) ? hz[p] : -hz[p];
        phiT += (t & 1) ? hz[12] : -hz[12];
#pragma unroll
        for (int l = 0; l < 8; ++l) {
            float phi = phiT;
            phi += (l & 1) ? hz[9]  : -hz[9];
            phi += (l & 2) ? hz[10] : -hz[10];
            phi += (l & 4) ? hz[11] : -hz[11];
            float sp, cp;
            __sincosf(phi, &sp, &cp);
            a[l] = (f2){a[l].x * cp - a[l].y * sp, a[l].x * sp + a[l].y * cp};
        }

        // ---- T4: CNOT round, D -> canonical (inverse suffix-parity gather) ----
        {
            f2* __restrict__ B = buf[pp]; pp ^= 1;
#pragma unroll
            for (int l = 0; l < 8; ++l)
                B[swz(((t >> 1) & 511) | (l << 9) | ((t & 1) << 12))] = a[l];
            __syncthreads();
#pragma unroll
            for (int l = 0; l < 8; ++l) {
                const int c0 = (t << 3) | l;
                a[l] = B[swz(c0 ^ (c0 >> 1))];
            }
        }
    }

    // ---- handoff: psi -> buf[0] (plain indexing; last round used buf[1]) ----
    f2* __restrict__ psi = buf[0];
#pragma unroll
    for (int l = 0; l < 8; ++l) psi[(t << 3) | l] = a[l];
    __syncthreads();

    // ---- quad phase: 32 rows of O per block, 16 waves/CU streaming ----
    // thread t owns cols [4t,4t+4) (float4 idx t) and [4096+4t,...) (idx t+1024)
    f2 rm[8];
#pragma unroll
    for (int c = 0; c < 4; ++c) rm[c]     = psi[4 * t + c];
#pragma unroll
    for (int c = 0; c < 4; ++c) rm[4 + c] = psi[4096 + 4 * t + c];

    float acc = 0.f;
    const int i0 = (int)blockIdx.x * QROWS;
#pragma unroll 2
    for (int rr = 0; rr < QROWS; ++rr) {
        const int i = i0 + rr;
        const f2 w = psi[i];   // uniform address -> LDS broadcast
        const floatx4* __restrict__ Or = (const floatx4*)(O + (size_t)i * DIM);
        const floatx4 o0 = __builtin_nontemporal_load(&Or[t]);
        const floatx4 o1 = __builtin_nontemporal_load(&Or[t + 1024]);
        acc = fmaf(o0.x, fmaf(w.x, rm[0].x, w.y * rm[0].y), acc);
        acc = fmaf(o0.y, fmaf(w.x, rm[1].x, w.y * rm[1].y), acc);
        acc = fmaf(o0.z, fmaf(w.x, rm[2].x, w.y * rm[2].y), acc);
        acc = fmaf(o0.w, fmaf(w.x, rm[3].x, w.y * rm[3].y), acc);
        acc = fmaf(o1.x, fmaf(w.x, rm[4].x, w.y * rm[4].y), acc);
        acc = fmaf(o1.y, fmaf(w.x, rm[5].x, w.y * rm[5].y), acc);
        acc = fmaf(o1.z, fmaf(w.x, rm[6].x, w.y * rm[6].y), acc);
        acc = fmaf(o1.w, fmaf(w.x, rm[7].x, w.y * rm[7].y), acc);
    }

    // ---- block reduction (16 waves) ----
#pragma unroll
    for (int off = 32; off > 0; off >>= 1) acc += __shfl_down(acc, off);
    __shared__ float wsum[SIMT / 64];
    const int lane = t & 63, w64 = t >> 6;
    if (lane == 0) wsum[w64] = acc;
    __syncthreads();
    if (t == 0) {
        float s = 0.f;
#pragma unroll
        for (int k = 0; k < SIMT / 64; ++k) s += wsum[k];
        partials[blockIdx.x] = s;
    }
}

// ---------------------------------------------------------------------------
// Reduce: sum the 256 per-block partials (fixed order, deterministic).
// ---------------------------------------------------------------------------
__global__ __launch_bounds__(256) void reduce_kernel(const float* __restrict__ partials,
                                                     float* __restrict__ out) {
    const int t = threadIdx.x;
    float acc = partials[t];
#pragma unroll
    for (int off = 32; off > 0; off >>= 1) acc += __shfl_down(acc, off);
    __shared__ float wsum[4];
    const int lane = t & 63, w = t >> 6;
    if (lane == 0) wsum[w] = acc;
    __syncthreads();
    if (t == 0) out[0] = wsum[0] + wsum[1] + wsum[2] + wsum[3];
}

extern "C" void kernel_launch(void* const* d_in, const int* in_sizes, int n_in,
                              void* d_out, int out_size, void* d_ws, size_t ws_size,
                              hipStream_t stream) {
    const float* params = (const float*)d_in[0];   // 208 fp32
    const float* O      = (const float*)d_in[1];   // 8192*8192 fp32
    float* out = (float*)d_out;

    float* partials = (float*)d_ws;   // 256 floats

    fused_kernel<<<NB, SIMT, 0, stream>>>(params, O, partials);
    reduce_kernel<<<1, 256, 0, stream>>>(partials, out);
}